// Round 9
// baseline (216.549 us; speedup 1.0000x reference)
//
#include <hip/hip_runtime.h>
#include <cstdint>
#include <cstddef>

// ws layout (float offsets)
#define WS_WBIG 0            // 3072*32 = 98304
#define WS_BMAT 98304        // bmatT: 24*640 = 15360
#define WS_BBIG 113664       // 24 (+pad to 64)
#define WS_ND   113728       // 8*8192*23 = 1507328
#define WS_ED   1621056      // 4*28672*23 = 2637824

// output offsets (floats)
#define OUT_IND 0
#define OUT_LAB 28672
#define OUT_LRP 57344
#define OUT_CRP 98304
#define OUT_MRP 122880
#define OUT_LRN 237568
#define OUT_CRN 339968
#define OUT_MRN 401408

__device__ __constant__ int d_pi[28] = {0,0,0,0,0,0,0,1,1,1,1,1,1,2,2,2,2,2,3,3,3,3,4,4,4,5,5,6};
__device__ __constant__ int d_pj[28] = {1,2,3,4,5,6,7,2,3,4,5,6,7,3,4,5,6,7,4,5,6,7,5,6,7,6,7,7};

__device__ __forceinline__ float wh_at(const float* wlr, const float* wcr, const float* wmr,
                                       int j, int h) {
  return (h < 5) ? wlr[j*5 + h] : (h < 8) ? wcr[j*3 + (h-5)] : wmr[j*14 + (h-8)];
}

// global -> LDS direct (16B per lane); LDS dest = wave-uniform base + lane*16
__device__ __forceinline__ void load_lds16(const float* g, float* l) {
  __builtin_amdgcn_global_load_lds((const __attribute__((address_space(1))) void*)g,
                                   (__attribute__((address_space(3))) void*)l, 16, 0, 0);
}

// ---------------- prep1: bmatT[24][640] and b_big ----------------
__global__ __launch_bounds__(256) void prep1(
    const float* __restrict__ w_rel, const float* __restrict__ w_ind2,
    const float* __restrict__ w_lr, const float* __restrict__ w_cr, const float* __restrict__ w_mr,
    const float* __restrict__ b_ind1, const float* __restrict__ b_ind2,
    const float* __restrict__ b_rel,
    const float* __restrict__ b_lr, const float* __restrict__ b_cr, const float* __restrict__ b_mr,
    float* __restrict__ bmat, float* __restrict__ bbig) {
  int bid = blockIdx.x, tid = threadIdx.x;
  if (bid < 128) {                         // T1 col m: bmatT[1+h][m] = sum_j Wrel2[m][j]*Wh[j][h]
    int m = bid;
    __shared__ float swr[512];
    const float* wr2 = w_rel + (size_t)(3072 + m)*512;
    swr[tid]       = wr2[tid];
    swr[tid + 256] = wr2[tid + 256];
    __syncthreads();
    int h = tid >> 3, q = tid & 7;
    if (h < 22) {
      float a = 0.f;
#pragma unroll 8
      for (int jj = 0; jj < 64; ++jj) {
        int j = jj*8 + q;
        a = fmaf(swr[j], wh_at(w_lr, w_cr, w_mr, j, h), a);
      }
      a += __shfl_xor(a, 1); a += __shfl_xor(a, 2); a += __shfl_xor(a, 4);
      if (q == 0) bmat[(1 + h)*640 + m] = a;
    }
    if (tid == 248) bmat[0*640 + m]  = w_ind2[m];
    if (tid == 249) bmat[23*640 + m] = 0.f;
  } else if (bid == 128) {                 // biases
    __shared__ float sbrel[512];
    for (int j = tid; j < 512; j += 256) {
      float a = b_rel[j];
#pragma unroll 4
      for (int m = 0; m < 128; ++m)
        a = fmaf(b_ind1[m], w_rel[(size_t)(3072 + m)*512 + j], a);
      sbrel[j] = a;
    }
    __syncthreads();
    int h = tid >> 3, q = tid & 7;
    if (h < 22) {
      float bh = (h < 5) ? b_lr[h] : (h < 8) ? b_cr[h-5] : b_mr[h-8];
      float a = 0.f;
#pragma unroll 8
      for (int jj = 0; jj < 64; ++jj) {
        int j = jj*8 + q;
        a = fmaf(sbrel[j], wh_at(w_lr, w_cr, w_mr, j, h), a);
      }
      a += __shfl_xor(a, 1); a += __shfl_xor(a, 2); a += __shfl_xor(a, 4);
      if (q == 0) bbig[1 + h] = a + bh;
    } else if (tid >= 248) {
      int q2 = tid & 7;
      float a = 0.f;
#pragma unroll
      for (int t = 0; t < 16; ++t)
        a = fmaf(b_ind1[q2*16 + t], w_ind2[q2*16 + t], a);
      a += __shfl_xor(a, 1); a += __shfl_xor(a, 2); a += __shfl_xor(a, 4);
      if (tid == 248) bbig[0]  = a + b_ind2[0];
      if (tid == 250) bbig[23] = 0.f;
    }
  } else {                                 // WhE: bmatT[n][128+j], bids 129..176
    int idx = (bid - 129)*256 + tid;
    int j = idx / 24, n = idx % 24;
    float v = (n >= 1 && n <= 22) ? wh_at(w_lr, w_cr, w_mr, j, n - 1) : 0.f;
    bmat[n*640 + 128 + j] = v;
  }
}

// ---------------- prep2: W_big[k][n] (pitch 32) = [W_ind1|W_rel][k] . bmatT[n][:]
__global__ __launch_bounds__(256) void prep2(
    const float* __restrict__ w_ind1, const float* __restrict__ w_rel,
    const float* __restrict__ bmat, float* __restrict__ wbig) {
  int g = blockIdx.x*256 + threadIdx.x;    // 294912 = 73728 outputs x 4 quarters
  int gid = g >> 2, q = g & 3;
  int k = gid / 24, n = gid % 24;
  float a = 0.f;
  if (n != 23) {
    const float* wr = w_rel + (size_t)k*512;
    const float* bn = bmat + n*640;
    if (q == 0) {
      const float* w1 = w_ind1 + (size_t)k*128;
#pragma unroll 8
      for (int i = 0; i < 128; ++i) a = fmaf(w1[i], bn[i], a);
#pragma unroll 8
      for (int j = 0; j < 32; ++j) a = fmaf(wr[j], bn[128 + j], a);
    } else {
      int j0 = 32 + (q - 1)*160;
#pragma unroll 8
      for (int jj = 0; jj < 160; ++jj) {
        int j = j0 + jj;
        a = fmaf(wr[j], bn[128 + j], a);
      }
    }
  }
  a += __shfl_xor(a, 1); a += __shfl_xor(a, 2);
  if (q == 0) wbig[(size_t)k*32 + n] = a;
}

// ---------------- kmain: 128 rows x 256-k chunk; NO DMA in loop; reg-staged X ----------------
// W chunk (256k x 32) staged to LDS once in prologue (DMA). X tile [128 rows][32 k] pitch-33
// (conflict-free, no swizzle), reg-staged: 4 coalesced dwordx4 loads issued BEFORE compute,
// ds_write after barrier (T14). Lane owns rows {l, l+64}; wave w owns k-slots {w*2, w*2+1}.
template<bool ISNODE>
__global__ __launch_bounds__(256, 2) void kmain(
    const float* __restrict__ nf, const float* __restrict__ intf,
    const float* __restrict__ wbig, float* __restrict__ ndp, float* __restrict__ edp) {
  __shared__ float smem[12800];            // 51.2 KB (reduce phase needs 512*25)
  float* XL = smem;                        // [128][33]
  float* WL = smem + 4224;                 // [256][32]
  const int tid = threadIdx.x;
  const int l = tid & 63;
  const int w = tid >> 6;
  const int bid = blockIdx.x;

  int rg, chunk;
  if (ISNODE) { rg = bid >> 3; chunk = bid & 7; }      // 64 rg x 8 chunks of 256k
  else        { rg = bid >> 2; chunk = bid & 3; }      // 224 rg x 4 chunks of 256k
  const int R0 = rg*128;
  const int kd0 = chunk*256;
  const int nsteps = 8;                                // 8 x 32 k

  const float* wchunk = wbig + (size_t)((ISNODE ? 0 : 2048) + kd0)*32;

  // X stage addressing: thread -> slot s = tid&7 (float4), rows rbase+32i, rbase = tid>>3
  const int s4 = (tid & 7)*4, rbase = tid >> 3;
  const float* xsrc[4];
#pragma unroll
  for (int i = 0; i < 4; ++i) {
    int grow = R0 + rbase + 32*i;
    const float* rp;
    if (ISNODE) rp = nf + (size_t)grow*2048;
    else {
      int b = grow / 28, p = grow % 28;
      rp = intf + (size_t)(b*64 + d_pi[p]*8 + d_pj[p])*1024;
    }
    xsrc[i] = rp + kd0 + s4;
  }

  // ---- prologue: stage W chunk (8 KB/wave via gload_lds) + X tile 0 (regs) ----
#pragma unroll
  for (int m = 0; m < 8; ++m)
    load_lds16(wchunk + (size_t)(w*512 + m*64 + l)*4, WL + (w*512 + m*64)*4);
  float4 v[4];
#pragma unroll
  for (int i = 0; i < 4; ++i) v[i] = *(const float4*)(xsrc[i]);
  asm volatile("s_waitcnt vmcnt(0)" ::: "memory");
#pragma unroll
  for (int i = 0; i < 4; ++i)
    *(float4*)(XL + (rbase + 32*i)*33 + s4) = v[i];
  __syncthreads();

  float acc0[23], acc1[23];
#pragma unroll
  for (int n = 0; n < 23; ++n) { acc0[n] = 0.f; acc1[n] = 0.f; }

#pragma unroll 1
  for (int t = 0; t < nsteps; ++t) {
    if (t + 1 < nsteps) {                  // issue next tile's loads early (hide under compute)
#pragma unroll
      for (int i = 0; i < 4; ++i) v[i] = *(const float4*)(xsrc[i] + (t + 1)*32);
    }
    // compute step t: wave w's k-slots q = w*2, w*2+1
#pragma unroll
    for (int kq = 0; kq < 2; ++kq) {
      int q = w*2 + kq;
      float4 x0 = *(const float4*)(XL + l*33 + q*4);
      float4 x1 = *(const float4*)(XL + (l + 64)*33 + q*4);
      const float* wr0 = WL + (size_t)(t*32 + q*4)*32;
#pragma unroll
      for (int e = 0; e < 4; ++e) {
        float xs0 = (e == 0) ? x0.x : (e == 1) ? x0.y : (e == 2) ? x0.z : x0.w;
        float xs1 = (e == 0) ? x1.x : (e == 1) ? x1.y : (e == 2) ? x1.z : x1.w;
        const float* wr = wr0 + e*32;      // broadcast ds_read_b128 x6
        float wreg[24];
#pragma unroll
        for (int v4 = 0; v4 < 6; ++v4) {
          float4 t4 = *(const float4*)(wr + v4*4);
          wreg[v4*4+0] = t4.x; wreg[v4*4+1] = t4.y; wreg[v4*4+2] = t4.z; wreg[v4*4+3] = t4.w;
        }
#pragma unroll
        for (int n = 0; n < 23; ++n) {
          acc0[n] = fmaf(xs0, wreg[n], acc0[n]);
          acc1[n] = fmaf(xs1, wreg[n], acc1[n]);
        }
      }
    }
    __syncthreads();                       // all waves done reading tile t (drains stage loads too)
    if (t + 1 < nsteps) {
#pragma unroll
      for (int i = 0; i < 4; ++i)
        *(float4*)(XL + (rbase + 32*i)*33 + s4) = v[i];
    }
    __syncthreads();                       // writes visible before next compute
  }

  // ---- epilogue: cross-wave reduce (pitch 25) -> coalesced partial store ----
  float* red = smem;
#pragma unroll
  for (int n = 0; n < 23; ++n) {
    red[(w*128 + l)*25 + n]      = acc0[n];
    red[(w*128 + l + 64)*25 + n] = acc1[n];
  }
  __syncthreads();
  float* outp = ISNODE ? (ndp + ((size_t)chunk*8192  + R0)*23)
                       : (edp + ((size_t)chunk*28672 + R0)*23);
  for (int g = tid; g < 128*23; g += 256) {
    int r = g / 23, n = g - r*23;
    float sum = red[r*25 + n] + red[(128 + r)*25 + n]
              + red[(256 + r)*25 + n] + red[(384 + r)*25 + n];
    outp[g] = sum;
  }
}

// ---------------- kcombine: one batch per block; sums 8 node / 4 edge partials ----------------
__global__ __launch_bounds__(256) void kcombine(
    const float* __restrict__ ndp, const float* __restrict__ edp,
    const float* __restrict__ bbig, const int* __restrict__ opairs,
    float* __restrict__ out) {
  __shared__ float snd[184];
  __shared__ int spos[8];
  int b = blockIdx.x, tid = threadIdx.x;
  if (tid < 184) {
    int o = tid / 23, n = tid % 23;
    float s = 0.f;
#pragma unroll
    for (int c = 0; c < 8; ++c)
      s += ndp[((size_t)c*8192 + b*8 + o)*23 + n];
    snd[tid] = s;
  } else if (tid < 192) {
    int r = tid - 184;
    int oi = opairs[b*16 + r*2], oj = opairs[b*16 + r*2 + 1];
    int a = min(oi, oj), bb = max(oi, oj);
    spos[r] = 7*a - (a*(a+1))/2 + bb - 1;
  }
  __syncthreads();
  for (int g = tid; g < 644; g += 256) {
    int p = g / 23, n = g % 23;
    float ed = 0.f;
#pragma unroll
    for (int c = 0; c < 4; ++c)
      ed += edp[((size_t)c*28672 + b*28 + p)*23 + n];
    float val = 0.5f*(snd[d_pi[p]*23 + n] + snd[d_pj[p]*23 + n]) + ed + bbig[n];
    int slot = -1, below = 0;
#pragma unroll
    for (int r = 0; r < 8; ++r) {
      int pl = spos[r];
      slot = (pl == p) ? r : slot;
      below += (pl < p) ? 1 : 0;
    }
    if (n == 0) {
      out[OUT_IND + b*28 + p] = 1.f/(1.f + expf(-val));
      out[OUT_LAB + b*28 + p] = (slot >= 0) ? 1.f : 0.f;
    } else {
      int h = n - 1;
      if (slot >= 0) {
        int rr = b*8 + slot;
        if (h < 5)      out[OUT_LRP + rr*5  + h]     = val;
        else if (h < 8) out[OUT_CRP + rr*3  + (h-5)] = val;
        else            out[OUT_MRP + rr*14 + (h-8)] = val;
      } else {
        int s = p - below;
        int rr = b*20 + s;
        if (h < 5)      out[OUT_LRN + rr*5  + h]     = val;
        else if (h < 8) out[OUT_CRN + rr*3  + (h-5)] = val;
        else            out[OUT_MRN + rr*14 + (h-8)] = val;
      }
    }
  }
}

extern "C" void kernel_launch(void* const* d_in, const int* in_sizes, int n_in,
                              void* d_out, int out_size, void* d_ws, size_t ws_size,
                              hipStream_t stream) {
  const float* nf     = (const float*)d_in[0];
  const float* intf   = (const float*)d_in[1];
  const int*   opairs = (const int*)d_in[2];
  const float* w_ind1 = (const float*)d_in[3];
  const float* b_ind1 = (const float*)d_in[4];
  const float* w_ind2 = (const float*)d_in[5];
  const float* b_ind2 = (const float*)d_in[6];
  const float* w_rel  = (const float*)d_in[7];
  const float* b_rel  = (const float*)d_in[8];
  const float* w_cr   = (const float*)d_in[9];
  const float* b_cr   = (const float*)d_in[10];
  const float* w_lr   = (const float*)d_in[11];
  const float* b_lr   = (const float*)d_in[12];
  const float* w_mr   = (const float*)d_in[13];
  const float* b_mr   = (const float*)d_in[14];
  float* out = (float*)d_out;
  float* ws  = (float*)d_ws;

  float* wbig = ws + WS_WBIG;
  float* bmat = ws + WS_BMAT;
  float* bbig = ws + WS_BBIG;
  float* ndp  = ws + WS_ND;
  float* edp  = ws + WS_ED;

  prep1<<<177, 256, 0, stream>>>(w_rel, w_ind2, w_lr, w_cr, w_mr,
                                 b_ind1, b_ind2, b_rel, b_lr, b_cr, b_mr, bmat, bbig);
  prep2<<<1152, 256, 0, stream>>>(w_ind1, w_rel, bmat, wbig);
  kmain<true ><<<512, 256, 0, stream>>>(nf, intf, wbig, ndp, edp);
  kmain<false><<<896, 256, 0, stream>>>(nf, intf, wbig, ndp, edp);
  kcombine<<<1024, 256, 0, stream>>>(ndp, edp, bbig, opairs, out);
}